// Round 7
// baseline (247.193 us; speedup 1.0000x reference)
//
#include <hip/hip_runtime.h>

// MHA forward: inputs fp32, output fp32. Internals bf16 MFMA.
// (0) cvt fp32->bf16 (x + 4 W's), (1) QKV gemm (bf16, global_load_lds;
// Q pre-scaled by 0.125*log2e), (2) causal flash-attention (S^T/O^T,
// exp2-domain softmax, unpaired reversed grid), (3) O-proj gemm -> fp32.

#define DMODEL 1024
#define NHEADS 16
#define DHEAD  64
#define SEQ    2048
#define BATCH  2
#define MROWS  (BATCH * SEQ)   // 4096

typedef __bf16 bf16x8 __attribute__((ext_vector_type(8)));
typedef __bf16 bf16x4 __attribute__((ext_vector_type(4)));
typedef float  f32x4  __attribute__((ext_vector_type(4)));

__device__ __forceinline__ f32x4 mfma16(bf16x8 a, bf16x8 b, f32x4 c) {
    return __builtin_amdgcn_mfma_f32_16x16x32_bf16(a, b, c, 0, 0, 0);
}

__device__ __forceinline__ bf16x8 ld8(const float* p) {
    const f32x4 a0 = *(const f32x4*)p;
    const f32x4 a1 = *(const f32x4*)(p + 4);
    bf16x8 v;
    v[0] = (__bf16)a0[0]; v[1] = (__bf16)a0[1];
    v[2] = (__bf16)a0[2]; v[3] = (__bf16)a0[3];
    v[4] = (__bf16)a1[0]; v[5] = (__bf16)a1[1];
    v[6] = (__bf16)a1[2]; v[7] = (__bf16)a1[3];
    return v;
}

// async global->LDS, 16 B per lane; LDS dest = wave-uniform base + lane*16
__device__ __forceinline__ void gll16(const __bf16* g, __bf16* l) {
    __builtin_amdgcn_global_load_lds(
        (const __attribute__((address_space(1))) void*)g,
        (__attribute__((address_space(3))) void*)l,
        16, 0, 0);
}

// ---------------------------------------------------------------------------
// fp32 -> bf16 conversion pass. y=0: x; y=1..4: W's -> wcat.
// ---------------------------------------------------------------------------
__global__ __launch_bounds__(256) void cvt_kernel(const float* __restrict__ x,
                                                  const float* __restrict__ Wq,
                                                  const float* __restrict__ Wk,
                                                  const float* __restrict__ Wv,
                                                  const float* __restrict__ Wo,
                                                  __bf16* __restrict__ xb,
                                                  __bf16* __restrict__ wcat) {
    const int y = blockIdx.y;
    const float* src;
    __bf16* dst;
    int nchunks;
    if (y == 0) { src = x; dst = xb; nchunks = (MROWS * DMODEL) / 8; }
    else {
        src = (y == 1) ? Wq : (y == 2) ? Wk : (y == 3) ? Wv : Wo;
        dst = wcat + (size_t)(y - 1) * DMODEL * DMODEL;
        nchunks = (DMODEL * DMODEL) / 8;
    }
    const int c = blockIdx.x * 256 + threadIdx.x;
    if (c < nchunks) *(bf16x8*)(dst + (size_t)c * 8) = ld8(src + (size_t)c * 8);
}

// ---------------------------------------------------------------------------
// Pure-bf16 GEMM: C[m][n] = scale * sum_k A[m][k] * W[n][k].
// 128x128 tile, BK=32, 256 threads, m97 structure (global_load_lds w=16).
// ---------------------------------------------------------------------------
template <typename TC>
__device__ __forceinline__ void gemm_bb_body(const __bf16* __restrict__ A,
                                             const __bf16* __restrict__ W,
                                             TC* __restrict__ C,
                                             int m0, int n0, float scale) {
    constexpr int K = DMODEL;
    __shared__ __align__(16) __bf16 As[128][32];  // NO pad (global_load_lds)
    __shared__ __align__(16) __bf16 Bs[128][32];

    const int tid  = threadIdx.x;
    const int lane = tid & 63;
    const int wave = tid >> 6;
    const int quad = lane >> 4;
    const int l16  = lane & 15;
    const int wm   = wave & 1;
    const int wn   = wave >> 1;

    const int srow = lane >> 2;          // 0..15
    const int scol = (lane & 3) * 8;

    const __bf16* a0p = A + (size_t)(m0 + wave * 16 + srow) * K + scol;
    const __bf16* a1p = A + (size_t)(m0 + 64 + wave * 16 + srow) * K + scol;
    const __bf16* b0p = W + (size_t)(n0 + wave * 16 + srow) * K + scol;
    const __bf16* b1p = W + (size_t)(n0 + 64 + wave * 16 + srow) * K + scol;

    f32x4 acc[4][4] = {};

    for (int k0 = 0; k0 < K; k0 += 32) {
        __syncthreads();
        gll16(a0p + k0, &As[wave * 16][0]);
        gll16(a1p + k0, &As[64 + wave * 16][0]);
        gll16(b0p + k0, &Bs[wave * 16][0]);
        gll16(b1p + k0, &Bs[64 + wave * 16][0]);
        __syncthreads();

        bf16x8 af[4], bfr[4];
#pragma unroll
        for (int i = 0; i < 4; ++i) {
            af[i]  = *(const bf16x8*)(&As[wm * 64 + i * 16 + l16][quad * 8]);
            bfr[i] = *(const bf16x8*)(&Bs[wn * 64 + i * 16 + l16][quad * 8]);
        }
#pragma unroll
        for (int mi = 0; mi < 4; ++mi)
#pragma unroll
            for (int ni = 0; ni < 4; ++ni)
                acc[mi][ni] = mfma16(af[mi], bfr[ni], acc[mi][ni]);
    }

    // C/D layout: col = l16, row = quad*4 + r
#pragma unroll
    for (int mi = 0; mi < 4; ++mi)
#pragma unroll
        for (int ni = 0; ni < 4; ++ni)
#pragma unroll
            for (int r = 0; r < 4; ++r) {
                int row = m0 + wm * 64 + mi * 16 + quad * 4 + r;
                int col = n0 + wn * 64 + ni * 16 + l16;
                C[(size_t)row * DMODEL + col] = (TC)(acc[mi][ni][r] * scale);
            }
}

// Q pre-scale: 1/sqrt(Dh) * log2(e) so attention scores are log2-domain.
#define QSCALE 0.1803368801111204f

__global__ __launch_bounds__(256) void qkv_kernel(const __bf16* __restrict__ X,
                                                  const __bf16* __restrict__ wcat,
                                                  __bf16* __restrict__ QKV) {
    const __bf16* W = wcat + (size_t)blockIdx.z * DMODEL * DMODEL;
    __bf16*       Y = QKV + (size_t)blockIdx.z * MROWS * DMODEL;
    const float scale = (blockIdx.z == 0) ? QSCALE : 1.0f;
    gemm_bb_body<__bf16>(X, W, Y, blockIdx.y * 128, blockIdx.x * 128, scale);
}

__global__ __launch_bounds__(256) void out_gemm_kernel(const __bf16* __restrict__ A,
                                                       const __bf16* __restrict__ W,
                                                       float* __restrict__ C) {
    gemm_bb_body<float>(A, W, C, blockIdx.y * 128, blockIdx.x * 128, 1.0f);
}

// ---------------------------------------------------------------------------
// Causal flash attention, S^T / O^T formulation, exp2-domain softmax.
// Grid: 64 q-tiles (32 rows each) x 32 bh; qt = 63 - blockIdx.x so the
// longest blocks dispatch first. Block = 128 threads (2 waves x 16 q).
// Main k-tiles (kt < qt) are provably unmasked; only kt == qt is masked.
// ---------------------------------------------------------------------------
__global__ __launch_bounds__(128) void attn_kernel(const __bf16* __restrict__ Q,
                                                   const __bf16* __restrict__ Kg,
                                                   const __bf16* __restrict__ Vg,
                                                   __bf16* __restrict__ O) {
    const int qt = 63 - blockIdx.x;  // biggest tiles first
    const int bh = blockIdx.y;
    const int b = bh >> 4, h = bh & 15;
    const size_t base = (size_t)b * SEQ * DMODEL + (size_t)h * DHEAD;

    const int tid  = threadIdx.x;
    const int lane = tid & 63;
    const int wave = tid >> 6;
    const int quad = lane >> 4;
    const int l16  = lane & 15;

    __shared__ __align__(16) __bf16 Ks[32][80];
    __shared__ __align__(16) __bf16 Vt[64][40];
    __shared__ __align__(16) __bf16 Ps[2][16][40];

    const int ldr = tid >> 2;
    const int c0  = (tid & 3) * 16;
    const int vcol = (((ldr >> 3) ^ (c0 >> 4)) << 3) | (ldr & 7);

    const int qrow = qt * 32 + wave * 16 + l16;

    // Q fragments (already scaled by 0.125*log2e at QKV epilogue)
    const bf16x8 qf0 = *(const bf16x8*)(Q + base + (size_t)qrow * DMODEL + quad * 8);
    const bf16x8 qf1 = *(const bf16x8*)(Q + base + (size_t)qrow * DMODEL + 32 + quad * 8);

    f32x4 oacc[4] = {};
    float m_i = -1e30f, l_i = 0.f;

    const __bf16* kp = Kg + base + (size_t)ldr * DMODEL + c0;
    const __bf16* vp = Vg + base + (size_t)ldr * DMODEL + c0;
    bf16x8 pk0 = *(const bf16x8*)(kp);
    bf16x8 pk1 = *(const bf16x8*)(kp + 8);
    bf16x8 pv0 = *(const bf16x8*)(vp);
    bf16x8 pv1 = *(const bf16x8*)(vp + 8);

    for (int kt = 0; kt <= qt; ++kt) {
        *(bf16x8*)(&Ks[ldr][c0])     = pk0;
        *(bf16x8*)(&Ks[ldr][c0 + 8]) = pk1;
#pragma unroll
        for (int i = 0; i < 8; ++i) {
            Vt[c0 + i][vcol]     = pv0[i];
            Vt[c0 + 8 + i][vcol] = pv1[i];
        }
        __syncthreads();

        if (kt < qt) {
            const __bf16* kp2 = Kg + base + (size_t)((kt + 1) * 32 + ldr) * DMODEL + c0;
            const __bf16* vp2 = Vg + base + (size_t)((kt + 1) * 32 + ldr) * DMODEL + c0;
            pk0 = *(const bf16x8*)(kp2);
            pk1 = *(const bf16x8*)(kp2 + 8);
            pv0 = *(const bf16x8*)(vp2);
            pv1 = *(const bf16x8*)(vp2 + 8);
        }

        const int k0 = kt * 32;
        const bool diag = (kt == qt);   // wave-uniform

        // S^T[kk][q] (log2 domain): A = K rows, B = Q^T
        const bf16x8 kf00 = *(const bf16x8*)(&Ks[l16][quad * 8]);
        const bf16x8 kf01 = *(const bf16x8*)(&Ks[l16][32 + quad * 8]);
        const bf16x8 kf10 = *(const bf16x8*)(&Ks[16 + l16][quad * 8]);
        const bf16x8 kf11 = *(const bf16x8*)(&Ks[16 + l16][32 + quad * 8]);
        f32x4 s0 = {}, s1 = {};
        s0 = mfma16(kf00, qf0, s0); s0 = mfma16(kf01, qf1, s0);
        s1 = mfma16(kf10, qf0, s1); s1 = mfma16(kf11, qf1, s1);

        float mx;
        bool ok[2][4];
        if (!diag) {
            float m0 = s0[0];
#pragma unroll
            for (int r = 1; r < 4; ++r) m0 = fmaxf(m0, s0[r]);
#pragma unroll
            for (int r = 0; r < 4; ++r) m0 = fmaxf(m0, s1[r]);
            mx = m0;
        } else {
            mx = -1e30f;
#pragma unroll
            for (int hh = 0; hh < 2; ++hh)
#pragma unroll
                for (int r = 0; r < 4; ++r) {
                    const int kk = k0 + hh * 16 + quad * 4 + r;
                    ok[hh][r] = (kk <= qrow);
                    const float v = hh ? s1[r] : s0[r];
                    mx = fmaxf(mx, ok[hh][r] ? v : -1e30f);
                }
        }
        mx = fmaxf(mx, __shfl_xor(mx, 16));
        mx = fmaxf(mx, __shfl_xor(mx, 32));
        const float mnew  = fmaxf(m_i, mx);
        const float alpha = exp2f(m_i - mnew);
        m_i = mnew;

        float p[2][4];
        float rs = 0.f;
        if (!diag) {
#pragma unroll
            for (int hh = 0; hh < 2; ++hh)
#pragma unroll
                for (int r = 0; r < 4; ++r) {
                    p[hh][r] = exp2f((hh ? s1[r] : s0[r]) - mnew);
                    rs += p[hh][r];
                }
        } else {
#pragma unroll
            for (int hh = 0; hh < 2; ++hh)
#pragma unroll
                for (int r = 0; r < 4; ++r) {
                    p[hh][r] = ok[hh][r] ? exp2f((hh ? s1[r] : s0[r]) - mnew) : 0.f;
                    rs += p[hh][r];
                }
        }
        rs += __shfl_xor(rs, 16);
        rs += __shfl_xor(rs, 32);
        l_i = l_i * alpha + rs;

        bf16x4 w0, w1;
#pragma unroll
        for (int r = 0; r < 4; ++r) { w0[r] = (__bf16)p[0][r]; w1[r] = (__bf16)p[1][r]; }
        *(bf16x4*)(&Ps[wave][l16][quad * 4])      = w0;
        *(bf16x4*)(&Ps[wave][l16][16 + quad * 4]) = w1;

        const bf16x8 pf = *(const bf16x8*)(&Ps[wave][l16][quad * 8]);
#pragma unroll
        for (int f = 0; f < 4; ++f) {
            const bf16x8 vf = *(const bf16x8*)(&Vt[f * 16 + l16][(quad ^ f) * 8]);
            oacc[f] = mfma16(vf, pf, oacc[f] * alpha);
        }
        __syncthreads();
    }

    const float inv = (l_i > 0.f) ? (1.f / l_i) : 0.f;
#pragma unroll
    for (int f = 0; f < 4; ++f) {
        bf16x4 o;
#pragma unroll
        for (int r = 0; r < 4; ++r) o[r] = (__bf16)(oacc[f][r] * inv);
        *(bf16x4*)(O + base + (size_t)qrow * DMODEL + f * 16 + quad * 4) = o;
    }
}

// ---------------------------------------------------------------------------
extern "C" void kernel_launch(void* const* d_in, const int* in_sizes, int n_in,
                              void* d_out, int out_size, void* d_ws, size_t ws_size,
                              hipStream_t stream) {
    const float* x  = (const float*)d_in[0];
    const float* Wq = (const float*)d_in[1];
    const float* Wk = (const float*)d_in[2];
    const float* Wv = (const float*)d_in[3];
    const float* Wo = (const float*)d_in[4];
    float* out = (float*)d_out;

    const size_t tm = (size_t)MROWS * DMODEL;    // 4M elems
    const size_t tw = (size_t)DMODEL * DMODEL;   // 1M elems
    __bf16* xb   = (__bf16*)d_ws;                // 4M
    __bf16* wcat = xb + tm;                      // 4M (Wq,Wk,Wv,Wo)
    __bf16* QKV  = wcat + 4 * tw;                // 12M (Q,K,V)
    __bf16* Q = QKV;
    __bf16* K = QKV + tm;
    __bf16* V = QKV + 2 * tm;                    // total 40 MB ws

    dim3 gc(2048, 5);
    cvt_kernel<<<gc, 256, 0, stream>>>(x, Wq, Wk, Wv, Wo, xb, wcat);

    dim3 g1(DMODEL / 128, MROWS / 128, 3);
    qkv_kernel<<<g1, 256, 0, stream>>>(xb, wcat, QKV);

    dim3 g2(SEQ / 32, BATCH * NHEADS);           // 64 x 32
    attn_kernel<<<g2, 128, 0, stream>>>(Q, K, V, /*O=*/Q);

    dim3 g3(DMODEL / 128, MROWS / 128);
    out_gemm_kernel<<<g3, 256, 0, stream>>>(/*O=*/Q, wcat + 3 * tw, out);
}

// Round 8
// 212.525 us; speedup vs baseline: 1.1631x; 1.1631x over previous
//
#include <hip/hip_runtime.h>

// MHA forward: inputs fp32, output fp32. Internals bf16 MFMA.
// (0) cvt fp32->bf16, (1) QKV gemm (bf16, global_load_lds; Q pre-scaled by
// 0.125*log2e), (2) causal flash-attention (S^T/O^T, exp2 softmax, balanced
// pairs, bh-major grid for XCD-L2 affinity), (3) O-proj gemm -> fp32.

#define DMODEL 1024
#define NHEADS 16
#define DHEAD  64
#define SEQ    2048
#define BATCH  2
#define MROWS  (BATCH * SEQ)   // 4096

typedef __bf16 bf16x8 __attribute__((ext_vector_type(8)));
typedef __bf16 bf16x4 __attribute__((ext_vector_type(4)));
typedef float  f32x4  __attribute__((ext_vector_type(4)));

__device__ __forceinline__ f32x4 mfma16(bf16x8 a, bf16x8 b, f32x4 c) {
    return __builtin_amdgcn_mfma_f32_16x16x32_bf16(a, b, c, 0, 0, 0);
}

__device__ __forceinline__ bf16x8 ld8(const float* p) {
    const f32x4 a0 = *(const f32x4*)p;
    const f32x4 a1 = *(const f32x4*)(p + 4);
    bf16x8 v;
    v[0] = (__bf16)a0[0]; v[1] = (__bf16)a0[1];
    v[2] = (__bf16)a0[2]; v[3] = (__bf16)a0[3];
    v[4] = (__bf16)a1[0]; v[5] = (__bf16)a1[1];
    v[6] = (__bf16)a1[2]; v[7] = (__bf16)a1[3];
    return v;
}

// async global->LDS, 16 B per lane; LDS dest = wave-uniform base + lane*16
__device__ __forceinline__ void gll16(const __bf16* g, __bf16* l) {
    __builtin_amdgcn_global_load_lds(
        (const __attribute__((address_space(1))) void*)g,
        (__attribute__((address_space(3))) void*)l,
        16, 0, 0);
}

// ---------------------------------------------------------------------------
// fp32 -> bf16 conversion pass. y=0: x; y=1..4: W's -> wcat.
// ---------------------------------------------------------------------------
__global__ __launch_bounds__(256) void cvt_kernel(const float* __restrict__ x,
                                                  const float* __restrict__ Wq,
                                                  const float* __restrict__ Wk,
                                                  const float* __restrict__ Wv,
                                                  const float* __restrict__ Wo,
                                                  __bf16* __restrict__ xb,
                                                  __bf16* __restrict__ wcat) {
    const int y = blockIdx.y;
    const float* src;
    __bf16* dst;
    int nchunks;
    if (y == 0) { src = x; dst = xb; nchunks = (MROWS * DMODEL) / 8; }
    else {
        src = (y == 1) ? Wq : (y == 2) ? Wk : (y == 3) ? Wv : Wo;
        dst = wcat + (size_t)(y - 1) * DMODEL * DMODEL;
        nchunks = (DMODEL * DMODEL) / 8;
    }
    const int c = blockIdx.x * 256 + threadIdx.x;
    if (c < nchunks) *(bf16x8*)(dst + (size_t)c * 8) = ld8(src + (size_t)c * 8);
}

// ---------------------------------------------------------------------------
// Pure-bf16 GEMM: C[m][n] = scale * sum_k A[m][k] * W[n][k].
// 128x128 tile, BK=32, 256 threads, m97 structure (global_load_lds w=16).
// ---------------------------------------------------------------------------
template <typename TC>
__device__ __forceinline__ void gemm_bb_body(const __bf16* __restrict__ A,
                                             const __bf16* __restrict__ W,
                                             TC* __restrict__ C,
                                             int m0, int n0, float scale) {
    constexpr int K = DMODEL;
    __shared__ __align__(16) __bf16 As[128][32];  // NO pad (global_load_lds)
    __shared__ __align__(16) __bf16 Bs[128][32];

    const int tid  = threadIdx.x;
    const int lane = tid & 63;
    const int wave = tid >> 6;
    const int quad = lane >> 4;
    const int l16  = lane & 15;
    const int wm   = wave & 1;
    const int wn   = wave >> 1;

    const int srow = lane >> 2;          // 0..15
    const int scol = (lane & 3) * 8;

    const __bf16* a0p = A + (size_t)(m0 + wave * 16 + srow) * K + scol;
    const __bf16* a1p = A + (size_t)(m0 + 64 + wave * 16 + srow) * K + scol;
    const __bf16* b0p = W + (size_t)(n0 + wave * 16 + srow) * K + scol;
    const __bf16* b1p = W + (size_t)(n0 + 64 + wave * 16 + srow) * K + scol;

    f32x4 acc[4][4] = {};

    for (int k0 = 0; k0 < K; k0 += 32) {
        __syncthreads();
        gll16(a0p + k0, &As[wave * 16][0]);
        gll16(a1p + k0, &As[64 + wave * 16][0]);
        gll16(b0p + k0, &Bs[wave * 16][0]);
        gll16(b1p + k0, &Bs[64 + wave * 16][0]);
        __syncthreads();

        bf16x8 af[4], bfr[4];
#pragma unroll
        for (int i = 0; i < 4; ++i) {
            af[i]  = *(const bf16x8*)(&As[wm * 64 + i * 16 + l16][quad * 8]);
            bfr[i] = *(const bf16x8*)(&Bs[wn * 64 + i * 16 + l16][quad * 8]);
        }
#pragma unroll
        for (int mi = 0; mi < 4; ++mi)
#pragma unroll
            for (int ni = 0; ni < 4; ++ni)
                acc[mi][ni] = mfma16(af[mi], bfr[ni], acc[mi][ni]);
    }

    // C/D layout: col = l16, row = quad*4 + r
#pragma unroll
    for (int mi = 0; mi < 4; ++mi)
#pragma unroll
        for (int ni = 0; ni < 4; ++ni)
#pragma unroll
            for (int r = 0; r < 4; ++r) {
                int row = m0 + wm * 64 + mi * 16 + quad * 4 + r;
                int col = n0 + wn * 64 + ni * 16 + l16;
                C[(size_t)row * DMODEL + col] = (TC)(acc[mi][ni][r] * scale);
            }
}

// Q pre-scale: 1/sqrt(Dh) * log2(e) so attention scores are log2-domain.
#define QSCALE 0.1803368801111204f

__global__ __launch_bounds__(256) void qkv_kernel(const __bf16* __restrict__ X,
                                                  const __bf16* __restrict__ wcat,
                                                  __bf16* __restrict__ QKV) {
    const __bf16* W = wcat + (size_t)blockIdx.z * DMODEL * DMODEL;
    __bf16*       Y = QKV + (size_t)blockIdx.z * MROWS * DMODEL;
    const float scale = (blockIdx.z == 0) ? QSCALE : 1.0f;
    gemm_bb_body<__bf16>(X, W, Y, blockIdx.y * 128, blockIdx.x * 128, scale);
}

__global__ __launch_bounds__(256) void out_gemm_kernel(const __bf16* __restrict__ A,
                                                       const __bf16* __restrict__ W,
                                                       float* __restrict__ C) {
    gemm_bb_body<float>(A, W, C, blockIdx.y * 128, blockIdx.x * 128, 1.0f);
}

// ---------------------------------------------------------------------------
// Causal flash attention, S^T / O^T, exp2 softmax, BALANCED PAIRS.
// Block = 128 threads (2 waves x 16 q-rows = 32-row q-tile); block (bh, pr)
// processes q-tiles pr and 63-pr -> constant 65 k-tiles per block (any
// placement is balanced). Grid is bh-major: linear id = pr*32 + bh, so
// id%8 = bh%8 -> each XCD hosts 4 distinct heads -> K/V working set 2 MB
// fits the 4 MB per-XCD L2 (K/V stream becomes L2-resident).
// Only the diagonal k-tile (kt == qt) applies the causal mask.
// ---------------------------------------------------------------------------
__global__ __launch_bounds__(128) void attn_kernel(const __bf16* __restrict__ Q,
                                                   const __bf16* __restrict__ Kg,
                                                   const __bf16* __restrict__ Vg,
                                                   __bf16* __restrict__ O) {
    const int bh = blockIdx.x;   // 0..31  (fast dim -> XCD affinity)
    const int pr = blockIdx.y;   // 0..31  (tile pair)
    const int b = bh >> 4, h = bh & 15;
    const size_t base = (size_t)b * SEQ * DMODEL + (size_t)h * DHEAD;

    const int tid  = threadIdx.x;
    const int lane = tid & 63;
    const int wave = tid >> 6;
    const int quad = lane >> 4;
    const int l16  = lane & 15;

    __shared__ __align__(16) __bf16 Ks[32][80];
    __shared__ __align__(16) __bf16 Vt[64][40];
    __shared__ __align__(16) __bf16 Ps[2][16][40];

    const int ldr = tid >> 2;
    const int c0  = (tid & 3) * 16;
    const int vcol = (((ldr >> 3) ^ (c0 >> 4)) << 3) | (ldr & 7);

#pragma unroll
    for (int sel = 0; sel < 2; ++sel) {
        const int qt = sel ? (63 - pr) : pr;
        const int qrow = qt * 32 + wave * 16 + l16;

        // Q fragments (already scaled by 0.125*log2e at QKV epilogue)
        const bf16x8 qf0 = *(const bf16x8*)(Q + base + (size_t)qrow * DMODEL + quad * 8);
        const bf16x8 qf1 = *(const bf16x8*)(Q + base + (size_t)qrow * DMODEL + 32 + quad * 8);

        f32x4 oacc[4] = {};
        float m_i = -1e30f, l_i = 0.f;

        const __bf16* kp = Kg + base + (size_t)ldr * DMODEL + c0;
        const __bf16* vp = Vg + base + (size_t)ldr * DMODEL + c0;
        bf16x8 pk0 = *(const bf16x8*)(kp);
        bf16x8 pk1 = *(const bf16x8*)(kp + 8);
        bf16x8 pv0 = *(const bf16x8*)(vp);
        bf16x8 pv1 = *(const bf16x8*)(vp + 8);

        for (int kt = 0; kt <= qt; ++kt) {
            *(bf16x8*)(&Ks[ldr][c0])     = pk0;
            *(bf16x8*)(&Ks[ldr][c0 + 8]) = pk1;
#pragma unroll
            for (int i = 0; i < 8; ++i) {
                Vt[c0 + i][vcol]     = pv0[i];
                Vt[c0 + 8 + i][vcol] = pv1[i];
            }
            __syncthreads();

            if (kt < qt) {
                const __bf16* kp2 = Kg + base + (size_t)((kt + 1) * 32 + ldr) * DMODEL + c0;
                const __bf16* vp2 = Vg + base + (size_t)((kt + 1) * 32 + ldr) * DMODEL + c0;
                pk0 = *(const bf16x8*)(kp2);
                pk1 = *(const bf16x8*)(kp2 + 8);
                pv0 = *(const bf16x8*)(vp2);
                pv1 = *(const bf16x8*)(vp2 + 8);
            }

            const int k0 = kt * 32;
            const bool diag = (kt == qt);   // wave-uniform

            // S^T[kk][q] (log2 domain): A = K rows, B = Q^T
            const bf16x8 kf00 = *(const bf16x8*)(&Ks[l16][quad * 8]);
            const bf16x8 kf01 = *(const bf16x8*)(&Ks[l16][32 + quad * 8]);
            const bf16x8 kf10 = *(const bf16x8*)(&Ks[16 + l16][quad * 8]);
            const bf16x8 kf11 = *(const bf16x8*)(&Ks[16 + l16][32 + quad * 8]);
            f32x4 s0 = {}, s1 = {};
            s0 = mfma16(kf00, qf0, s0); s0 = mfma16(kf01, qf1, s0);
            s1 = mfma16(kf10, qf0, s1); s1 = mfma16(kf11, qf1, s1);

            float mx;
            bool ok[2][4];
            if (!diag) {
                float m0 = s0[0];
#pragma unroll
                for (int r = 1; r < 4; ++r) m0 = fmaxf(m0, s0[r]);
#pragma unroll
                for (int r = 0; r < 4; ++r) m0 = fmaxf(m0, s1[r]);
                mx = m0;
            } else {
                mx = -1e30f;
#pragma unroll
                for (int hh = 0; hh < 2; ++hh)
#pragma unroll
                    for (int r = 0; r < 4; ++r) {
                        const int kk = k0 + hh * 16 + quad * 4 + r;
                        ok[hh][r] = (kk <= qrow);
                        const float v = hh ? s1[r] : s0[r];
                        mx = fmaxf(mx, ok[hh][r] ? v : -1e30f);
                    }
            }
            mx = fmaxf(mx, __shfl_xor(mx, 16));
            mx = fmaxf(mx, __shfl_xor(mx, 32));
            const float mnew  = fmaxf(m_i, mx);
            const float alpha = exp2f(m_i - mnew);
            m_i = mnew;

            float p[2][4];
            float rs = 0.f;
            if (!diag) {
#pragma unroll
                for (int hh = 0; hh < 2; ++hh)
#pragma unroll
                    for (int r = 0; r < 4; ++r) {
                        p[hh][r] = exp2f((hh ? s1[r] : s0[r]) - mnew);
                        rs += p[hh][r];
                    }
            } else {
#pragma unroll
                for (int hh = 0; hh < 2; ++hh)
#pragma unroll
                    for (int r = 0; r < 4; ++r) {
                        p[hh][r] = ok[hh][r] ? exp2f((hh ? s1[r] : s0[r]) - mnew) : 0.f;
                        rs += p[hh][r];
                    }
            }
            rs += __shfl_xor(rs, 16);
            rs += __shfl_xor(rs, 32);
            l_i = l_i * alpha + rs;

            bf16x4 w0, w1;
#pragma unroll
            for (int r = 0; r < 4; ++r) { w0[r] = (__bf16)p[0][r]; w1[r] = (__bf16)p[1][r]; }
            *(bf16x4*)(&Ps[wave][l16][quad * 4])      = w0;
            *(bf16x4*)(&Ps[wave][l16][16 + quad * 4]) = w1;

            const bf16x8 pf = *(const bf16x8*)(&Ps[wave][l16][quad * 8]);
#pragma unroll
            for (int f = 0; f < 4; ++f) {
                const bf16x8 vf = *(const bf16x8*)(&Vt[f * 16 + l16][(quad ^ f) * 8]);
                oacc[f] = mfma16(vf, pf, oacc[f] * alpha);
            }
            __syncthreads();
        }

        const float inv = (l_i > 0.f) ? (1.f / l_i) : 0.f;
#pragma unroll
        for (int f = 0; f < 4; ++f) {
            bf16x4 o;
#pragma unroll
            for (int r = 0; r < 4; ++r) o[r] = (__bf16)(oacc[f][r] * inv);
            *(bf16x4*)(O + base + (size_t)qrow * DMODEL + f * 16 + quad * 4) = o;
        }
    }
}

// ---------------------------------------------------------------------------
extern "C" void kernel_launch(void* const* d_in, const int* in_sizes, int n_in,
                              void* d_out, int out_size, void* d_ws, size_t ws_size,
                              hipStream_t stream) {
    const float* x  = (const float*)d_in[0];
    const float* Wq = (const float*)d_in[1];
    const float* Wk = (const float*)d_in[2];
    const float* Wv = (const float*)d_in[3];
    const float* Wo = (const float*)d_in[4];
    float* out = (float*)d_out;

    const size_t tm = (size_t)MROWS * DMODEL;    // 4M elems
    const size_t tw = (size_t)DMODEL * DMODEL;   // 1M elems
    __bf16* xb   = (__bf16*)d_ws;                // 4M
    __bf16* wcat = xb + tm;                      // 4M (Wq,Wk,Wv,Wo)
    __bf16* QKV  = wcat + 4 * tw;                // 12M (Q,K,V)
    __bf16* Q = QKV;
    __bf16* K = QKV + tm;
    __bf16* V = QKV + 2 * tm;                    // total 40 MB ws

    dim3 gc(2048, 5);
    cvt_kernel<<<gc, 256, 0, stream>>>(x, Wq, Wk, Wv, Wo, xb, wcat);

    dim3 g1(DMODEL / 128, MROWS / 128, 3);
    qkv_kernel<<<g1, 256, 0, stream>>>(xb, wcat, QKV);

    dim3 g2(BATCH * NHEADS, SEQ / 64);           // bh-major: 32 x 32
    attn_kernel<<<g2, 128, 0, stream>>>(Q, K, V, /*O=*/Q);

    dim3 g3(DMODEL / 128, MROWS / 128);
    out_gemm_kernel<<<g3, 256, 0, stream>>>(/*O=*/Q, wcat + 3 * tw, out);
}

// Round 9
// 203.223 us; speedup vs baseline: 1.2164x; 1.0458x over previous
//
#include <hip/hip_runtime.h>

// MHA forward: inputs fp32, output fp32. Internals bf16 MFMA.
// (0) cvt fp32->bf16, (1) QKV gemm (bf16, global_load_lds; Q pre-scaled by
// 0.125*log2e), (2) causal flash-attention (S^T/O^T, exp2 softmax, unpaired,
// grid (bh, qt-desc) for balance + XCD-L2 affinity), (3) O-proj gemm -> fp32.

#define DMODEL 1024
#define NHEADS 16
#define DHEAD  64
#define SEQ    2048
#define BATCH  2
#define MROWS  (BATCH * SEQ)   // 4096

typedef __bf16 bf16x8 __attribute__((ext_vector_type(8)));
typedef __bf16 bf16x4 __attribute__((ext_vector_type(4)));
typedef float  f32x4  __attribute__((ext_vector_type(4)));

__device__ __forceinline__ f32x4 mfma16(bf16x8 a, bf16x8 b, f32x4 c) {
    return __builtin_amdgcn_mfma_f32_16x16x32_bf16(a, b, c, 0, 0, 0);
}

__device__ __forceinline__ bf16x8 ld8(const float* p) {
    const f32x4 a0 = *(const f32x4*)p;
    const f32x4 a1 = *(const f32x4*)(p + 4);
    bf16x8 v;
    v[0] = (__bf16)a0[0]; v[1] = (__bf16)a0[1];
    v[2] = (__bf16)a0[2]; v[3] = (__bf16)a0[3];
    v[4] = (__bf16)a1[0]; v[5] = (__bf16)a1[1];
    v[6] = (__bf16)a1[2]; v[7] = (__bf16)a1[3];
    return v;
}

// async global->LDS, 16 B per lane; LDS dest = wave-uniform base + lane*16
__device__ __forceinline__ void gll16(const __bf16* g, __bf16* l) {
    __builtin_amdgcn_global_load_lds(
        (const __attribute__((address_space(1))) void*)g,
        (__attribute__((address_space(3))) void*)l,
        16, 0, 0);
}

// ---------------------------------------------------------------------------
// fp32 -> bf16 conversion pass. y=0: x; y=1..4: W's -> wcat.
// ---------------------------------------------------------------------------
__global__ __launch_bounds__(256) void cvt_kernel(const float* __restrict__ x,
                                                  const float* __restrict__ Wq,
                                                  const float* __restrict__ Wk,
                                                  const float* __restrict__ Wv,
                                                  const float* __restrict__ Wo,
                                                  __bf16* __restrict__ xb,
                                                  __bf16* __restrict__ wcat) {
    const int y = blockIdx.y;
    const float* src;
    __bf16* dst;
    int nchunks;
    if (y == 0) { src = x; dst = xb; nchunks = (MROWS * DMODEL) / 8; }
    else {
        src = (y == 1) ? Wq : (y == 2) ? Wk : (y == 3) ? Wv : Wo;
        dst = wcat + (size_t)(y - 1) * DMODEL * DMODEL;
        nchunks = (DMODEL * DMODEL) / 8;
    }
    const int c = blockIdx.x * 256 + threadIdx.x;
    if (c < nchunks) *(bf16x8*)(dst + (size_t)c * 8) = ld8(src + (size_t)c * 8);
}

// ---------------------------------------------------------------------------
// Pure-bf16 GEMM: C[m][n] = scale * sum_k A[m][k] * W[n][k].
// 128x128 tile, BK=32, 256 threads, m97 structure (global_load_lds w=16).
// ---------------------------------------------------------------------------
template <typename TC>
__device__ __forceinline__ void gemm_bb_body(const __bf16* __restrict__ A,
                                             const __bf16* __restrict__ W,
                                             TC* __restrict__ C,
                                             int m0, int n0, float scale) {
    constexpr int K = DMODEL;
    __shared__ __align__(16) __bf16 As[128][32];  // NO pad (global_load_lds)
    __shared__ __align__(16) __bf16 Bs[128][32];

    const int tid  = threadIdx.x;
    const int lane = tid & 63;
    const int wave = tid >> 6;
    const int quad = lane >> 4;
    const int l16  = lane & 15;
    const int wm   = wave & 1;
    const int wn   = wave >> 1;

    const int srow = lane >> 2;          // 0..15
    const int scol = (lane & 3) * 8;

    const __bf16* a0p = A + (size_t)(m0 + wave * 16 + srow) * K + scol;
    const __bf16* a1p = A + (size_t)(m0 + 64 + wave * 16 + srow) * K + scol;
    const __bf16* b0p = W + (size_t)(n0 + wave * 16 + srow) * K + scol;
    const __bf16* b1p = W + (size_t)(n0 + 64 + wave * 16 + srow) * K + scol;

    f32x4 acc[4][4] = {};

    for (int k0 = 0; k0 < K; k0 += 32) {
        __syncthreads();
        gll16(a0p + k0, &As[wave * 16][0]);
        gll16(a1p + k0, &As[64 + wave * 16][0]);
        gll16(b0p + k0, &Bs[wave * 16][0]);
        gll16(b1p + k0, &Bs[64 + wave * 16][0]);
        __syncthreads();

        bf16x8 af[4], bfr[4];
#pragma unroll
        for (int i = 0; i < 4; ++i) {
            af[i]  = *(const bf16x8*)(&As[wm * 64 + i * 16 + l16][quad * 8]);
            bfr[i] = *(const bf16x8*)(&Bs[wn * 64 + i * 16 + l16][quad * 8]);
        }
#pragma unroll
        for (int mi = 0; mi < 4; ++mi)
#pragma unroll
            for (int ni = 0; ni < 4; ++ni)
                acc[mi][ni] = mfma16(af[mi], bfr[ni], acc[mi][ni]);
    }

    // C/D layout: col = l16, row = quad*4 + r
#pragma unroll
    for (int mi = 0; mi < 4; ++mi)
#pragma unroll
        for (int ni = 0; ni < 4; ++ni)
#pragma unroll
            for (int r = 0; r < 4; ++r) {
                int row = m0 + wm * 64 + mi * 16 + quad * 4 + r;
                int col = n0 + wn * 64 + ni * 16 + l16;
                C[(size_t)row * DMODEL + col] = (TC)(acc[mi][ni][r] * scale);
            }
}

// Q pre-scale: 1/sqrt(Dh) * log2(e) so attention scores are log2-domain.
#define QSCALE 0.1803368801111204f

__global__ __launch_bounds__(256) void qkv_kernel(const __bf16* __restrict__ X,
                                                  const __bf16* __restrict__ wcat,
                                                  __bf16* __restrict__ QKV) {
    const __bf16* W = wcat + (size_t)blockIdx.z * DMODEL * DMODEL;
    __bf16*       Y = QKV + (size_t)blockIdx.z * MROWS * DMODEL;
    const float scale = (blockIdx.z == 0) ? QSCALE : 1.0f;
    gemm_bb_body<__bf16>(X, W, Y, blockIdx.y * 128, blockIdx.x * 128, scale);
}

__global__ __launch_bounds__(256) void out_gemm_kernel(const __bf16* __restrict__ A,
                                                       const __bf16* __restrict__ W,
                                                       float* __restrict__ C) {
    gemm_bb_body<float>(A, W, C, blockIdx.y * 128, blockIdx.x * 128, 1.0f);
}

// ---------------------------------------------------------------------------
// Causal flash attention, S^T / O^T, exp2 softmax, UNPAIRED.
// Block = 128 threads (2 waves x 16 q-rows = 32-row q-tile).
// Grid (x=bh 32, y=64), qt = 63 - y: long blocks dispatch first; co-resident
// blocks on a CU have ids differing by 256 -> qt differing by 8 (long/short
// mix, per-CU work within ~11%); id%8 = bh%8 keeps per-XCD K/V working set
// at 4 heads = 2 MB < 4 MB L2 (FETCH_SIZE 12 MB measured in round 8).
// 2048 blocks x 2 waves = 4096 waves = 50% occupancy ceiling (was 25%).
// Only the diagonal k-tile (kt == qt) applies the causal mask.
// ---------------------------------------------------------------------------
__global__ __launch_bounds__(128) void attn_kernel(const __bf16* __restrict__ Q,
                                                   const __bf16* __restrict__ Kg,
                                                   const __bf16* __restrict__ Vg,
                                                   __bf16* __restrict__ O) {
    const int bh = blockIdx.x;        // 0..31 (fast dim -> XCD affinity)
    const int qt = 63 - blockIdx.y;   // 0..63, biggest tiles first
    const int b = bh >> 4, h = bh & 15;
    const size_t base = (size_t)b * SEQ * DMODEL + (size_t)h * DHEAD;

    const int tid  = threadIdx.x;
    const int lane = tid & 63;
    const int wave = tid >> 6;
    const int quad = lane >> 4;
    const int l16  = lane & 15;

    __shared__ __align__(16) __bf16 Ks[32][80];
    __shared__ __align__(16) __bf16 Vt[64][40];
    __shared__ __align__(16) __bf16 Ps[2][16][40];

    const int ldr = tid >> 2;
    const int c0  = (tid & 3) * 16;
    const int vcol = (((ldr >> 3) ^ (c0 >> 4)) << 3) | (ldr & 7);

    const int qrow = qt * 32 + wave * 16 + l16;

    // Q fragments (already scaled by 0.125*log2e at QKV epilogue)
    const bf16x8 qf0 = *(const bf16x8*)(Q + base + (size_t)qrow * DMODEL + quad * 8);
    const bf16x8 qf1 = *(const bf16x8*)(Q + base + (size_t)qrow * DMODEL + 32 + quad * 8);

    f32x4 oacc[4] = {};
    float m_i = -1e30f, l_i = 0.f;

    const __bf16* kp = Kg + base + (size_t)ldr * DMODEL + c0;
    const __bf16* vp = Vg + base + (size_t)ldr * DMODEL + c0;
    bf16x8 pk0 = *(const bf16x8*)(kp);
    bf16x8 pk1 = *(const bf16x8*)(kp + 8);
    bf16x8 pv0 = *(const bf16x8*)(vp);
    bf16x8 pv1 = *(const bf16x8*)(vp + 8);

    for (int kt = 0; kt <= qt; ++kt) {
        *(bf16x8*)(&Ks[ldr][c0])     = pk0;
        *(bf16x8*)(&Ks[ldr][c0 + 8]) = pk1;
#pragma unroll
        for (int i = 0; i < 8; ++i) {
            Vt[c0 + i][vcol]     = pv0[i];
            Vt[c0 + 8 + i][vcol] = pv1[i];
        }
        __syncthreads();

        if (kt < qt) {
            const __bf16* kp2 = Kg + base + (size_t)((kt + 1) * 32 + ldr) * DMODEL + c0;
            const __bf16* vp2 = Vg + base + (size_t)((kt + 1) * 32 + ldr) * DMODEL + c0;
            pk0 = *(const bf16x8*)(kp2);
            pk1 = *(const bf16x8*)(kp2 + 8);
            pv0 = *(const bf16x8*)(vp2);
            pv1 = *(const bf16x8*)(vp2 + 8);
        }

        const int k0 = kt * 32;
        const bool diag = (kt == qt);   // wave-uniform

        // S^T[kk][q] (log2 domain): A = K rows, B = Q^T
        const bf16x8 kf00 = *(const bf16x8*)(&Ks[l16][quad * 8]);
        const bf16x8 kf01 = *(const bf16x8*)(&Ks[l16][32 + quad * 8]);
        const bf16x8 kf10 = *(const bf16x8*)(&Ks[16 + l16][quad * 8]);
        const bf16x8 kf11 = *(const bf16x8*)(&Ks[16 + l16][32 + quad * 8]);
        f32x4 s0 = {}, s1 = {};
        s0 = mfma16(kf00, qf0, s0); s0 = mfma16(kf01, qf1, s0);
        s1 = mfma16(kf10, qf0, s1); s1 = mfma16(kf11, qf1, s1);

        float mx;
        bool ok[2][4];
        if (!diag) {
            float m0 = s0[0];
#pragma unroll
            for (int r = 1; r < 4; ++r) m0 = fmaxf(m0, s0[r]);
#pragma unroll
            for (int r = 0; r < 4; ++r) m0 = fmaxf(m0, s1[r]);
            mx = m0;
        } else {
            mx = -1e30f;
#pragma unroll
            for (int hh = 0; hh < 2; ++hh)
#pragma unroll
                for (int r = 0; r < 4; ++r) {
                    const int kk = k0 + hh * 16 + quad * 4 + r;
                    ok[hh][r] = (kk <= qrow);
                    const float v = hh ? s1[r] : s0[r];
                    mx = fmaxf(mx, ok[hh][r] ? v : -1e30f);
                }
        }
        mx = fmaxf(mx, __shfl_xor(mx, 16));
        mx = fmaxf(mx, __shfl_xor(mx, 32));
        const float mnew  = fmaxf(m_i, mx);
        const float alpha = exp2f(m_i - mnew);
        m_i = mnew;

        float p[2][4];
        float rs = 0.f;
        if (!diag) {
#pragma unroll
            for (int hh = 0; hh < 2; ++hh)
#pragma unroll
                for (int r = 0; r < 4; ++r) {
                    p[hh][r] = exp2f((hh ? s1[r] : s0[r]) - mnew);
                    rs += p[hh][r];
                }
        } else {
#pragma unroll
            for (int hh = 0; hh < 2; ++hh)
#pragma unroll
                for (int r = 0; r < 4; ++r) {
                    p[hh][r] = ok[hh][r] ? exp2f((hh ? s1[r] : s0[r]) - mnew) : 0.f;
                    rs += p[hh][r];
                }
        }
        rs += __shfl_xor(rs, 16);
        rs += __shfl_xor(rs, 32);
        l_i = l_i * alpha + rs;

        bf16x4 w0, w1;
#pragma unroll
        for (int r = 0; r < 4; ++r) { w0[r] = (__bf16)p[0][r]; w1[r] = (__bf16)p[1][r]; }
        *(bf16x4*)(&Ps[wave][l16][quad * 4])      = w0;
        *(bf16x4*)(&Ps[wave][l16][16 + quad * 4]) = w1;

        const bf16x8 pf = *(const bf16x8*)(&Ps[wave][l16][quad * 8]);
#pragma unroll
        for (int f = 0; f < 4; ++f) {
            const bf16x8 vf = *(const bf16x8*)(&Vt[f * 16 + l16][(quad ^ f) * 8]);
            oacc[f] = mfma16(vf, pf, oacc[f] * alpha);
        }
        __syncthreads();
    }

    const float inv = (l_i > 0.f) ? (1.f / l_i) : 0.f;
#pragma unroll
    for (int f = 0; f < 4; ++f) {
        bf16x4 o;
#pragma unroll
        for (int r = 0; r < 4; ++r) o[r] = (__bf16)(oacc[f][r] * inv);
        *(bf16x4*)(O + base + (size_t)qrow * DMODEL + f * 16 + quad * 4) = o;
    }
}

// ---------------------------------------------------------------------------
extern "C" void kernel_launch(void* const* d_in, const int* in_sizes, int n_in,
                              void* d_out, int out_size, void* d_ws, size_t ws_size,
                              hipStream_t stream) {
    const float* x  = (const float*)d_in[0];
    const float* Wq = (const float*)d_in[1];
    const float* Wk = (const float*)d_in[2];
    const float* Wv = (const float*)d_in[3];
    const float* Wo = (const float*)d_in[4];
    float* out = (float*)d_out;

    const size_t tm = (size_t)MROWS * DMODEL;    // 4M elems
    const size_t tw = (size_t)DMODEL * DMODEL;   // 1M elems
    // QKV at ws base (round-5 placement), then xb, then wcat.
    __bf16* QKV  = (__bf16*)d_ws;                // 12M (Q,K,V)
    __bf16* xb   = QKV + 3 * tm;                 // 4M
    __bf16* wcat = xb + tm;                      // 4M (Wq,Wk,Wv,Wo)
    __bf16* Q = QKV;
    __bf16* K = QKV + tm;
    __bf16* V = QKV + 2 * tm;                    // total 40 MB ws

    dim3 gc(2048, 5);
    cvt_kernel<<<gc, 256, 0, stream>>>(x, Wq, Wk, Wv, Wo, xb, wcat);

    dim3 g1(DMODEL / 128, MROWS / 128, 3);
    qkv_kernel<<<g1, 256, 0, stream>>>(xb, wcat, QKV);

    dim3 g2(BATCH * NHEADS, SEQ / 32);           // (bh, y): qt = 63 - y
    attn_kernel<<<g2, 128, 0, stream>>>(Q, K, V, /*O=*/Q);

    dim3 g3(DMODEL / 128, MROWS / 128);
    out_gemm_kernel<<<g3, 256, 0, stream>>>(/*O=*/Q, wcat + 3 * tw, out);
}